// Round 13
// baseline (98.942 us; speedup 1.0000x reference)
//
#include <hip/hip_runtime.h>

// Direct-to-fragment separable projector v4 (128x64 per wave).
// R12: 94.3us total = 40.5 harness ws-poison fill (fixed) + ~37 k_proj + rest.
// k_proj ran 2x above issue floor; 64x64-quadrant layout costs 16 wave-exp-sets
// per block-kstep. R13: 2-wave blocks, wave = 128 rows x 64 cols (A-frags x4,
// B-frags x2) -> 12 sets/block (-25% exp work); NS=63/PER=320 -> 1008 blocks,
// 4 blocks/CU. accs 8x16 = 128 VGPR; budget ~246 @ launch_bounds(128,2).

#define S 128
#define NS 63            // 62 x 320 + 1 x 160 atoms, both /16
#define PER 320
#define BLOCK 128        // 2 waves; wave w covers cols [w*64, w*64+64), all rows

typedef _Float16 f16;
typedef _Float16 f16x2 __attribute__((ext_vector_type(2)));
typedef _Float16 f16x8 __attribute__((ext_vector_type(8)));
typedef float floatx16 __attribute__((ext_vector_type(16)));

#if __has_builtin(__builtin_amdgcn_exp2f)
#define FAST_EXP2(x) __builtin_amdgcn_exp2f(x)
#else
#define FAST_EXP2(x) exp2f(x)
#endif
#if __has_builtin(__builtin_amdgcn_rcpf)
#define FAST_RCP(x) __builtin_amdgcn_rcpf(x)
#else
#define FAST_RCP(x) (1.0f / (x))
#endif

static __device__ __forceinline__ f16x2 PKRTZ(float a, float b) {
#if __has_builtin(__builtin_amdgcn_cvt_pkrtz)
    return __builtin_bit_cast(f16x2, __builtin_amdgcn_cvt_pkrtz(a, b));
#else
    return (f16x2){(f16)a, (f16)b};
#endif
}

union frag_u { f16x8 v; f16x2 h[4]; };

__global__ __launch_bounds__(BLOCK, 2) void k_proj(
    const float* __restrict__ mol,   // (B, A, 3)
    const float* __restrict__ stds,  // (A)
    const float* __restrict__ dens,  // (A)
    f16* __restrict__ part,          // (B*NS, 128*128) f16 partials, frag order
    int B, int A)
{
    __shared__ float4 sP[PER];       // (x, y, k=-0.5*log2e/var, c2=log2(coef))

    const int ks   = blockIdx.x;
    const int b    = blockIdx.y;
    const int tid  = threadIdx.x;
    const int lane = tid & 63;
    const int wav  = tid >> 6;       // 0..1: column half
    const int l31  = lane & 31;
    const int hi   = lane >> 5;

    const int a0  = ks * PER;
    const int a1  = min(a0 + PER, A);
    const int cnt = a1 - a0;          // 320 or 160, both /16

    for (int i = tid; i < cnt; i += BLOCK) {
        const int a = a0 + i;
        const size_t idx = (size_t)b * A + a;
        float x  = mol[idx * 3 + 0];
        float y  = mol[idx * 3 + 1];
        float v  = stds[a] * stds[a];
        float rv = FAST_RCP(v);
        sP[i] = make_float4(x, y, -0.72134752044448f * rv,
                            __log2f(dens[a] * 0.15915494309189535f * rv));
    }
    __syncthreads();   // the only barrier

    const float py0 = (float)l31 - 63.5f;               // A row, tile 0 (rows 0-31)
    const float px0 = (float)(wav * 64 + l31) - 63.5f;  // B col, this wave's tile 0

    floatx16 acc[4][2];
#pragma unroll
    for (int r = 0; r < 4; ++r)
#pragma unroll
        for (int cb = 0; cb < 2; ++cb) acc[r][cb] = (floatx16){0.f};

    const int nk = cnt >> 4;          // even (20 or 10)
    const float4* sp = sP + hi * 8;

    // one kstep of 16 atoms; lane's k-half params in pp[0..7].
    // arg(d + 32m) = arg(d) + 64m*(k*d) + 1024*m^2*k  -> 2 independent fma each.
    auto kstep = [&](const float4 (&pp)[8]) {
        frag_u A0, A1, A2, A3, B0, B1;
#pragma unroll
        for (int jp = 0; jp < 4; ++jp) {
            float ea0[2], ea1[2], ea2[2], ea3[2], eb0[2], eb1[2];
#pragma unroll
            for (int u = 0; u < 2; ++u) {
                float4 p = pp[2 * jp + u];
                float dy = py0 - p.y;
                float t  = p.z * dy;
                float g0 = fmaf(t, dy, p.w);
                float g1 = fmaf(1024.0f, p.z, fmaf( 64.0f, t, g0));
                float g2 = fmaf(4096.0f, p.z, fmaf(128.0f, t, g0));
                float g3 = fmaf(9216.0f, p.z, fmaf(192.0f, t, g0));
                ea0[u] = FAST_EXP2(g0);
                ea1[u] = FAST_EXP2(g1);
                ea2[u] = FAST_EXP2(g2);
                ea3[u] = FAST_EXP2(g3);
                float dx = px0 - p.x;
                float s  = p.z * dx;
                float h0 = s * dx;
                float h1 = fmaf(1024.0f, p.z, fmaf(64.0f, s, h0));
                eb0[u] = FAST_EXP2(h0);
                eb1[u] = FAST_EXP2(h1);
            }
            A0.h[jp] = PKRTZ(ea0[0], ea0[1]);
            A1.h[jp] = PKRTZ(ea1[0], ea1[1]);
            A2.h[jp] = PKRTZ(ea2[0], ea2[1]);
            A3.h[jp] = PKRTZ(ea3[0], ea3[1]);
            B0.h[jp] = PKRTZ(eb0[0], eb0[1]);
            B1.h[jp] = PKRTZ(eb1[0], eb1[1]);
        }
        acc[0][0] = __builtin_amdgcn_mfma_f32_32x32x16_f16(A0.v, B0.v, acc[0][0], 0, 0, 0);
        acc[0][1] = __builtin_amdgcn_mfma_f32_32x32x16_f16(A0.v, B1.v, acc[0][1], 0, 0, 0);
        acc[1][0] = __builtin_amdgcn_mfma_f32_32x32x16_f16(A1.v, B0.v, acc[1][0], 0, 0, 0);
        acc[1][1] = __builtin_amdgcn_mfma_f32_32x32x16_f16(A1.v, B1.v, acc[1][1], 0, 0, 0);
        acc[2][0] = __builtin_amdgcn_mfma_f32_32x32x16_f16(A2.v, B0.v, acc[2][0], 0, 0, 0);
        acc[2][1] = __builtin_amdgcn_mfma_f32_32x32x16_f16(A2.v, B1.v, acc[2][1], 0, 0, 0);
        acc[3][0] = __builtin_amdgcn_mfma_f32_32x32x16_f16(A3.v, B0.v, acc[3][0], 0, 0, 0);
        acc[3][1] = __builtin_amdgcn_mfma_f32_32x32x16_f16(A3.v, B1.v, acc[3][1], 0, 0, 0);
    };

    // software pipeline, x2-unrolled (nk even): prefetch next kstep's params
    float4 c[8], n[8];
#pragma unroll
    for (int j = 0; j < 8; ++j) c[j] = sp[j];
    for (int s = 0; s < nk; s += 2) {
        const float4* sp1 = sp + (size_t)(s + 1) * 16;
#pragma unroll
        for (int j = 0; j < 8; ++j) n[j] = sp1[j];
        kstep(c);
        if (s + 2 < nk) {
            const float4* sp2 = sp + (size_t)(s + 2) * 16;
#pragma unroll
            for (int j = 0; j < 8; ++j) c[j] = sp2[j];
        }
        kstep(n);
    }

    // f16 partial store, frag order: idx = (r*4 + c)*1024 + lane*16 + reg,
    // image tile (r rows, c cols), c = wav*2 + cb (waves write disjoint tiles).
    f16* base = part + ((size_t)(b * NS + ks)) * (S * S) + lane * 16;
#pragma unroll
    for (int r = 0; r < 4; ++r) {
#pragma unroll
        for (int cb = 0; cb < 2; ++cb) {
            f16* pq = base + (size_t)(r * 4 + (wav * 2 + cb)) * 1024;
            frag_u lo, hiv;
#pragma unroll
            for (int jp = 0; jp < 4; ++jp) {
                lo.h[jp]  = PKRTZ(acc[r][cb][2 * jp],     acc[r][cb][2 * jp + 1]);
                hiv.h[jp] = PKRTZ(acc[r][cb][2 * jp + 8], acc[r][cb][2 * jp + 9]);
            }
            *(f16x8*)(pq + 0) = lo.v;
            *(f16x8*)(pq + 8) = hiv.v;
        }
    }
}

// sum NS f16 partials per batch (f16x8 coalesced reads), un-permute, write f32.
__global__ __launch_bounds__(256) void k_reduce(const f16* __restrict__ part,
                                                float* __restrict__ out) {
    const int b  = blockIdx.z;
    const int f8 = (blockIdx.x * 256 + threadIdx.x) * 8;   // frag-order base idx

    const f16* src = part + (size_t)b * NS * (S * S) + f8;
    float s0[8] = {0.f}, s1[8] = {0.f};
    int s = 0;
    for (; s + 1 < NS; s += 2) {
        f16x8 v0 = *(const f16x8*)&src[(size_t)s * (S * S)];
        f16x8 v1 = *(const f16x8*)&src[(size_t)(s + 1) * (S * S)];
#pragma unroll
        for (int i = 0; i < 8; ++i) { s0[i] += (float)v0[i]; s1[i] += (float)v1[i]; }
    }
    if (s < NS) {
        f16x8 v0 = *(const f16x8*)&src[(size_t)s * (S * S)];
#pragma unroll
        for (int i = 0; i < 8; ++i) s0[i] += (float)v0[i];
    }

    // decode f8 = tile*1024 + lane*16 + reg0; tile = r*4 + c (32x32 tiles)
    const int reg0 = f8 & 15;
    const int lane = (f8 >> 4) & 63;
    const int tile = f8 >> 10;
    const int r    = tile >> 2;
    const int cc   = tile & 3;
    // mfma_32x32 C/D: col = lane&31, row = (reg&3) + 8*(reg>>2) + 4*(lane>>5)
    const int rowb = r * 32 + 4 * (lane >> 5);
    const int col  = cc * 32 + (lane & 31);
#pragma unroll
    for (int i = 0; i < 8; ++i) {
        const int reg = reg0 + i;
        const int row = rowb + (reg & 3) + 8 * (reg >> 2);
        out[((size_t)b * S + row) * S + col] = s0[i] + s1[i];
    }
}

extern "C" void kernel_launch(void* const* d_in, const int* in_sizes, int n_in,
                              void* d_out, int out_size, void* d_ws, size_t ws_size,
                              hipStream_t stream) {
    const float* mol  = (const float*)d_in[0];
    const float* stds = (const float*)d_in[1];
    const float* dens = (const float*)d_in[2];
    float* out = (float*)d_out;

    const int A = in_sizes[1];             // 20000
    const int B = in_sizes[0] / (A * 3);   // 16

    f16* part = (f16*)d_ws;                // B*NS*16384*2 = 31.5 MB

    k_proj<<<dim3(NS, B), dim3(BLOCK), 0, stream>>>(mol, stds, dens, part, B, A);
    k_reduce<<<dim3((S * S) / (256 * 8), 1, B), dim3(256), 0, stream>>>(part, out);
}